// Round 10
// baseline (190.259 us; speedup 1.0000x reference)
//
#include <hip/hip_runtime.h>
#include <hip/hip_bf16.h>

typedef __bf16 bf16;
typedef __bf16 bf16x4 __attribute__((ext_vector_type(4)));
typedef __bf16 bf16x8 __attribute__((ext_vector_type(8)));
typedef float  f32x4  __attribute__((ext_vector_type(4)));

#define DEVI static __device__ __forceinline__

constexpr int NB = 4;
constexpr int N1 = 4096;
constexpr int N2 = 2048;
constexpr int D  = 256;   // DIM1 = DIM2 = DK

DEVI f32x4 mfma16(bf16x8 a, bf16x8 b, f32x4 c) {
  return __builtin_amdgcn_mfma_f32_16x16x32_bf16(a, b, c, 0, 0, 0);
}

typedef const __attribute__((address_space(1))) void* gas_t;
typedef __attribute__((address_space(3))) void* las_t;

DEVI void gload_lds16(const void* g, void* l) {
  __builtin_amdgcn_global_load_lds((gas_t)g, (las_t)l, 16, 0, 0);
}

DEVI void fence_sched() { __builtin_amdgcn_sched_barrier(0); }

// ---------------------------------------------------------------------------
// Q projection with hi/lo bf16 split for near-fp32 accuracy on the fp32 Q out.
// ---------------------------------------------------------------------------
__global__ __launch_bounds__(256)
void projQ_kernel(const float* __restrict__ A, const float* __restrict__ Bm,
                  const float* __restrict__ bias,
                  float* __restrict__ outF, bf16* __restrict__ out1,
                  bf16* __restrict__ out2)
{
  __shared__ bf16 Ah[128][64], Al[128][64];
  __shared__ bf16 Bh[64][64],  Bl[64][64];
  const int tid  = threadIdx.x;
  const int lane = tid & 63, wid = tid >> 6;
  const int wr = wid >> 1, wc = wid & 1;
  const int m0 = blockIdx.x * 128, n0 = blockIdx.y * 64;

  f32x4 acc[4][2];
#pragma unroll
  for (int i = 0; i < 4; ++i)
#pragma unroll
    for (int j = 0; j < 2; ++j) acc[i][j] = f32x4{0.f, 0.f, 0.f, 0.f};

  for (int kt = 0; kt < 4; ++kt) {
    const int k0 = kt * 64;
    if (kt) __syncthreads();
#pragma unroll
    for (int i = 0; i < 8; ++i) {
      int idx = i * 256 + tid;
      int r = idx >> 4, c4 = idx & 15;
      const float4 v = *(const float4*)(A + (size_t)(m0 + r) * D + k0 + c4 * 4);
      bf16x4 h, l;
      h[0] = (bf16)v.x; h[1] = (bf16)v.y; h[2] = (bf16)v.z; h[3] = (bf16)v.w;
      l[0] = (bf16)(v.x - (float)h[0]); l[1] = (bf16)(v.y - (float)h[1]);
      l[2] = (bf16)(v.z - (float)h[2]); l[3] = (bf16)(v.w - (float)h[3]);
      *(bf16x4*)&Ah[r][c4 * 4] = h;
      *(bf16x4*)&Al[r][c4 * 4] = l;
    }
#pragma unroll
    for (int i = 0; i < 4; ++i) {
      int idx = i * 256 + tid;
      int r = idx >> 4, c4 = idx & 15;
      const float4 v = *(const float4*)(Bm + (size_t)(n0 + r) * D + k0 + c4 * 4);
      bf16x4 h, l;
      h[0] = (bf16)v.x; h[1] = (bf16)v.y; h[2] = (bf16)v.z; h[3] = (bf16)v.w;
      l[0] = (bf16)(v.x - (float)h[0]); l[1] = (bf16)(v.y - (float)h[1]);
      l[2] = (bf16)(v.z - (float)h[2]); l[3] = (bf16)(v.w - (float)h[3]);
      *(bf16x4*)&Bh[r][c4 * 4] = h;
      *(bf16x4*)&Bl[r][c4 * 4] = l;
    }
    __syncthreads();
#pragma unroll
    for (int kc = 0; kc < 2; ++kc) {
      const int ko = kc * 32 + (lane >> 4) * 8;
      bf16x8 ah[4], al[4];
#pragma unroll
      for (int mf = 0; mf < 4; ++mf) {
        ah[mf] = *(bf16x8*)&Ah[wr * 64 + mf * 16 + (lane & 15)][ko];
        al[mf] = *(bf16x8*)&Al[wr * 64 + mf * 16 + (lane & 15)][ko];
      }
#pragma unroll
      for (int nf = 0; nf < 2; ++nf) {
        bf16x8 bh = *(bf16x8*)&Bh[wc * 32 + nf * 16 + (lane & 15)][ko];
        bf16x8 bl = *(bf16x8*)&Bl[wc * 32 + nf * 16 + (lane & 15)][ko];
#pragma unroll
        for (int mf = 0; mf < 4; ++mf) {
          acc[mf][nf] = mfma16(ah[mf], bh, acc[mf][nf]);
          acc[mf][nf] = mfma16(ah[mf], bl, acc[mf][nf]);
          acc[mf][nf] = mfma16(al[mf], bh, acc[mf][nf]);
        }
      }
    }
  }

#pragma unroll
  for (int nf = 0; nf < 2; ++nf) {
    const int col = n0 + wc * 32 + nf * 16 + (lane & 15);
    const float bcol = bias[col];
#pragma unroll
    for (int mf = 0; mf < 4; ++mf) {
#pragma unroll
      for (int r = 0; r < 4; ++r) {
        const int row = m0 + wr * 64 + mf * 16 + (lane >> 4) * 4 + r;
        float v = acc[mf][nf][r] + bcol;
        outF[(size_t)row * D + col] = v;
        out1[(size_t)row * D + col] = (bf16)v;
        out2[(size_t)row * D + col] = (bf16)tanhf(v);
      }
    }
  }
}

// ---------------------------------------------------------------------------
// K / V^T projections (plain bf16 MFMA).
// ---------------------------------------------------------------------------
template<int MODE>
__global__ __launch_bounds__(256)
void proj_kernel(const float* __restrict__ A, const float* __restrict__ Bm,
                 const float* __restrict__ bias,
                 bf16* __restrict__ out1, bf16* __restrict__ out2)
{
  __shared__ bf16 As[128][64];
  __shared__ bf16 Bs[64][64];
  const int tid  = threadIdx.x;
  const int lane = tid & 63, wid = tid >> 6;
  const int wr = wid >> 1, wc = wid & 1;
  const int m0 = blockIdx.x * 128, n0 = blockIdx.y * 64;

  f32x4 acc[4][2];
#pragma unroll
  for (int i = 0; i < 4; ++i)
#pragma unroll
    for (int j = 0; j < 2; ++j) acc[i][j] = f32x4{0.f, 0.f, 0.f, 0.f};

  for (int kt = 0; kt < 4; ++kt) {
    const int k0 = kt * 64;
    if (kt) __syncthreads();
#pragma unroll
    for (int i = 0; i < 8; ++i) {
      int idx = i * 256 + tid;
      int r = idx >> 4, c4 = idx & 15;
      const float4 v = *(const float4*)(A + (size_t)(m0 + r) * D + k0 + c4 * 4);
      bf16x4 bv; bv[0] = (bf16)v.x; bv[1] = (bf16)v.y; bv[2] = (bf16)v.z; bv[3] = (bf16)v.w;
      *(bf16x4*)&As[r][c4 * 4] = bv;
    }
#pragma unroll
    for (int i = 0; i < 4; ++i) {
      int idx = i * 256 + tid;
      int r = idx >> 4, c4 = idx & 15;
      const float4 v = *(const float4*)(Bm + (size_t)(n0 + r) * D + k0 + c4 * 4);
      bf16x4 bv; bv[0] = (bf16)v.x; bv[1] = (bf16)v.y; bv[2] = (bf16)v.z; bv[3] = (bf16)v.w;
      *(bf16x4*)&Bs[r][c4 * 4] = bv;
    }
    __syncthreads();
#pragma unroll
    for (int kc = 0; kc < 2; ++kc) {
      const int ko = kc * 32 + (lane >> 4) * 8;
      bf16x8 a[4];
#pragma unroll
      for (int mf = 0; mf < 4; ++mf)
        a[mf] = *(bf16x8*)&As[wr * 64 + mf * 16 + (lane & 15)][ko];
#pragma unroll
      for (int nf = 0; nf < 2; ++nf) {
        bf16x8 bb = *(bf16x8*)&Bs[wc * 32 + nf * 16 + (lane & 15)][ko];
#pragma unroll
        for (int mf = 0; mf < 4; ++mf) acc[mf][nf] = mfma16(a[mf], bb, acc[mf][nf]);
      }
    }
  }

#pragma unroll
  for (int nf = 0; nf < 2; ++nf) {
    const int col = n0 + wc * 32 + nf * 16 + (lane & 15);
    float bcol = 0.f;
    if constexpr (MODE == 1) bcol = bias[col];
#pragma unroll
    for (int mf = 0; mf < 4; ++mf) {
#pragma unroll
      for (int r = 0; r < 4; ++r) {
        const int row = m0 + wr * 64 + mf * 16 + (lane >> 4) * 4 + r;
        float v = acc[mf][nf][r];
        if constexpr (MODE == 1) {
          v += bcol;
          out1[(size_t)row * D + col] = (bf16)v;
          out2[(size_t)row * D + col] = (bf16)tanhf(v);
        } else {
          v += bias[row];  // row = dk
          out1[(size_t)(col >> 12) * (D * N1) + (size_t)row * N1 + (col & 4095)] = (bf16)v;
        }
      }
    }
  }
}

// ---------------------------------------------------------------------------
// Scores: e -> E bf16, partial row sums.
// NEW: 256 threads, 4 waves (2n x 2m), wave tile 64x64 -> LDS reads drop to
// 2x staged bytes on both operands (was 4x on A). acc = 128 VGPR (dual).
// Same 128x128 block tile, BK=32, dbuf, counted vmcnt(8), swizzle unchanged.
// ---------------------------------------------------------------------------
__global__ __launch_bounds__(256, 2)
void scores_kernel(const bf16* __restrict__ Qb, const bf16* __restrict__ tQb,
                   const bf16* __restrict__ Kb, const bf16* __restrict__ tKb,
                   bf16* __restrict__ E, float* __restrict__ partials)
{
  __shared__ bf16 SM[2][4][128][32];   // buf, {Qs,tQs,Ks,tKs}
  __shared__ float rowpart[128][2];
  const int tid = threadIdx.x, lane = tid & 63, wid = tid >> 6;
  const int wr = wid >> 1;       // n half (0..1)
  const int wc = wid & 1;        // m half (0..1)
  const int lo16 = lane & 15, hi = lane >> 4;
  const int mt = blockIdx.x, nt = blockIdx.y, b = blockIdx.z;
  const int RQ = b * N2 + nt * 128;
  const int RK = b * N1 + mt * 128;

  f32x4 accS[4][4], accP[4][4];
#pragma unroll
  for (int i = 0; i < 4; ++i)
#pragma unroll
    for (int j = 0; j < 4; ++j) {
      accS[i][j] = f32x4{0.f, 0.f, 0.f, 0.f};
      accP[i][j] = f32x4{0.f, 0.f, 0.f, 0.f};
    }

  auto stage = [&](int kt, int buf) {
#pragma unroll
    for (int i = 0; i < 2; ++i) {
      const int c = i * 256 + tid;          // chunk 0..511 per array
      const int row = c >> 2;               // 0..127
      const int soff = kt * 32 + (((c & 3) ^ ((row >> 1) & 3)) << 3);
      char* dst = (char*)&SM[buf][0][0][0] + c * 16;
      gload_lds16(Qb  + (size_t)(RQ + row) * D + soff, dst);
      gload_lds16(tQb + (size_t)(RQ + row) * D + soff, dst + 8192);
      gload_lds16(Kb  + (size_t)(RK + row) * D + soff, dst + 16384);
      gload_lds16(tKb + (size_t)(RK + row) * D + soff, dst + 24576);
    }
  };

  auto cpt = [&](int buf) {
    bf16x8 aS[4], aT[4];
#pragma unroll
    for (int mf = 0; mf < 4; ++mf) {
      const int row = wr * 64 + mf * 16 + lo16;
      const int ko = (hi ^ ((row >> 1) & 3)) << 3;
      aS[mf] = *(bf16x8*)&SM[buf][0][row][ko];
      aT[mf] = *(bf16x8*)&SM[buf][1][row][ko];
    }
#pragma unroll
    for (int nf = 0; nf < 4; ++nf) {
      const int row = wc * 64 + nf * 16 + lo16;
      const int ko = (hi ^ ((row >> 1) & 3)) << 3;
      bf16x8 bS = *(bf16x8*)&SM[buf][2][row][ko];
      bf16x8 bT = *(bf16x8*)&SM[buf][3][row][ko];
#pragma unroll
      for (int mf = 0; mf < 4; ++mf) {
        accS[mf][nf] = mfma16(aS[mf], bS, accS[mf][nf]);
        accP[mf][nf] = mfma16(aT[mf], bT, accP[mf][nf]);
      }
    }
  };

  stage(0, 0);
  fence_sched();
  int cur = 0;
#pragma unroll
  for (int kt = 0; kt < 8; ++kt) {
    if (kt < 7) {
      stage(kt + 1, cur ^ 1);
      fence_sched();
      asm volatile("s_waitcnt vmcnt(8)\n\ts_barrier" ::: "memory");
    } else {
      asm volatile("s_waitcnt vmcnt(0)\n\ts_barrier" ::: "memory");
    }
    __builtin_amdgcn_s_setprio(1);
    cpt(cur);
    __builtin_amdgcn_s_setprio(0);
    asm volatile("s_barrier" ::: "memory");
    cur ^= 1;
  }

  // epilogue
#pragma unroll
  for (int mf = 0; mf < 4; ++mf) {
    f32x4 rs = f32x4{0.f, 0.f, 0.f, 0.f};
#pragma unroll
    for (int nf = 0; nf < 4; ++nf) {
      const int m_g = mt * 128 + wc * 64 + nf * 16 + lo16;
#pragma unroll
      for (int r = 0; r < 4; ++r) {
        const int n_g = b * N2 + nt * 128 + wr * 64 + mf * 16 + hi * 4 + r;
        float s = accS[mf][nf][r] * (accP[mf][nf][r] + 1.0f) * 0.03125f;
        float e = __expf(s);
        E[(size_t)n_g * N1 + m_g] = (bf16)e;
        rs[r] += e;
      }
    }
#pragma unroll
    for (int r = 0; r < 4; ++r) {
      float v = rs[r];
      v += __shfl_xor(v, 1); v += __shfl_xor(v, 2);
      v += __shfl_xor(v, 4); v += __shfl_xor(v, 8);
      if (lo16 == 0)
        rowpart[wr * 64 + mf * 16 + hi * 4 + r][wc] = v;
    }
  }
  __syncthreads();
  if (tid < 128) {
    float p = rowpart[tid][0] + rowpart[tid][1];
    partials[(size_t)(b * N2 + nt * 128 + tid) * 32 + mt] = p;
  }
}

// ---------------------------------------------------------------------------
// Q_hat = (E @ V) * rinv over FULL K=4096 + fused attn finalize.
// NEW: no partQ / reduceQ. BM=32 n x 256 dk; 256 threads, 4 waves dk-split
// (wave tile 32n x 64dk). E [32][64] (4KB) + V [256][64] (32KB) both staged
// via gload_lds, XOR-swizzled, double-buffered (72KB LDS).
// Grid 256 blocks, XCD-chunked: xcd=blk&7, b=xcd>>1, nt=(xcd&1)*32+slot ->
// each XCD's V-batch (2MB) is L2-resident.
// Counted vmcnt, fenced issue order [stage(ms+1):9 | BAR1 | cpt(LDS-only) |
// attnwrite(readback + 2 stores) | BAR2]:
//   BAR1(ms) outstanding newer than stage(ms): stores(ms-1) x2 + stage(ms+1)
//   x9 = 11 -> vmcnt(11); ms=0: 9 (stage(0) drained by prologue); ms=63: 2.
// ---------------------------------------------------------------------------
__global__ __launch_bounds__(256)
void qhat_kernel(const bf16* __restrict__ E, const bf16* __restrict__ Vt,
                 const float* __restrict__ partials,
                 float* __restrict__ attn, float* __restrict__ Qhat)
{
  __shared__ bf16 Es[2][32][64];     // 8 KB
  __shared__ bf16 Vs[2][256][64];    // 64 KB
  __shared__ float rowinv[32];
  const int tid = threadIdx.x, lane = tid & 63, wid = tid >> 6;
  const int lo16 = lane & 15, hi = lane >> 4;
  const int xcd  = blockIdx.x & 7;
  const int slot = blockIdx.x >> 3;          // 0..31
  const int b    = xcd >> 1;
  const int nt   = (xcd & 1) * 32 + slot;    // 0..63
  const int n0   = nt * 32;
  const size_t nbase = (size_t)b * N2 + n0;
  const bf16* vb = Vt + (size_t)b * (D * N1);

  // staging coords
  const int erow = tid >> 3;                 // 0..31
  const int ephy = tid & 7;                  // phys chunk
  const int elg  = ephy ^ (erow & 7);        // logical chunk (involution)

  if (tid < 32) {
    const float* pr = partials + (nbase + tid) * 32;
    f32x4 s4 = *(const f32x4*)pr;
#pragma unroll
    for (int j = 1; j < 8; ++j) s4 += *(const f32x4*)(pr + j * 4);
    rowinv[tid] = 1.0f / (s4[0] + s4[1] + s4[2] + s4[3]);
  }

  auto stage = [&](int ms, int buf) {
    gload_lds16(E + (nbase + erow) * N1 + ms * 64 + elg * 8,
                (char*)&Es[buf][0][0] + tid * 16);
#pragma unroll
    for (int i = 0; i < 8; ++i) {
      const int c = i * 256 + tid;
      const int row = c >> 3;                // dk 0..255
      const int lg = (c & 7) ^ (row & 7);
      gload_lds16(vb + (size_t)row * N1 + ms * 64 + lg * 8,
                  (char*)&Vs[buf][0][0] + c * 16);
    }
  };

  f32x4 acc[2][4];
#pragma unroll
  for (int i = 0; i < 2; ++i)
#pragma unroll
    for (int j = 0; j < 4; ++j) acc[i][j] = f32x4{0.f, 0.f, 0.f, 0.f};

  auto cpt = [&](int buf) {
#pragma unroll
    for (int kc = 0; kc < 2; ++kc) {
      bf16x8 a[2];
#pragma unroll
      for (int mf = 0; mf < 2; ++mf) {
        const int row = mf * 16 + lo16;
        a[mf] = *(bf16x8*)((char*)&Es[buf][0][0] + row * 128 +
                           (((kc * 4 + hi) ^ (row & 7)) << 4));
      }
#pragma unroll
      for (int nf = 0; nf < 4; ++nf) {
        const int row = wid * 64 + nf * 16 + lo16;
        bf16x8 bb = *(bf16x8*)((char*)&Vs[buf][0][0] + row * 128 +
                               (((kc * 4 + hi) ^ (row & 7)) << 4));
        acc[0][nf] = mfma16(a[0], bb, acc[0][nf]);
        acc[1][nf] = mfma16(a[1], bb, acc[1][nf]);
      }
    }
  };

  auto attnwrite = [&](int ms, int buf) {
    bf16x8 ev = *(bf16x8*)((char*)&Es[buf][0][0] + tid * 16);
    const float inv = rowinv[erow];
    float v[8];
#pragma unroll
    for (int j = 0; j < 8; ++j) v[j] = (float)ev[j] * inv;
    float* dst = attn + (nbase + erow) * N1 + ms * 64 + elg * 8;
    float4 w0 = {v[0], v[1], v[2], v[3]};
    float4 w1 = {v[4], v[5], v[6], v[7]};
    *(float4*)(dst)     = w0;
    *(float4*)(dst + 4) = w1;
  };

  stage(0, 0);
  fence_sched();
  __syncthreads();   // drains stage(0) + rowinv ds_write

  int buf = 0;
  for (int ms = 0; ms < 64; ++ms) {
    if (ms < 63) { stage(ms + 1, buf ^ 1); fence_sched(); }
    if (ms == 0)
      asm volatile("s_waitcnt vmcnt(9)\n\ts_barrier" ::: "memory");
    else if (ms < 63)
      asm volatile("s_waitcnt vmcnt(11)\n\ts_barrier" ::: "memory");
    else
      asm volatile("s_waitcnt vmcnt(2)\n\ts_barrier" ::: "memory");
    __builtin_amdgcn_s_setprio(1);
    cpt(buf);
    __builtin_amdgcn_s_setprio(0);
    attnwrite(ms, buf);
    asm volatile("s_barrier" ::: "memory");   // LDS reads done before restage
    buf ^= 1;
  }

  // epilogue: Qhat fp32 = acc * rinv
#pragma unroll
  for (int mf = 0; mf < 2; ++mf)
#pragma unroll
    for (int r = 0; r < 4; ++r) {
      const int lr = mf * 16 + hi * 4 + r;
      const float inv = rowinv[lr];
#pragma unroll
      for (int nf = 0; nf < 4; ++nf) {
        const int dk = wid * 64 + nf * 16 + lo16;
        Qhat[(nbase + lr) * D + dk] = acc[mf][nf][r] * inv;
      }
    }
}

// ---------------------------------------------------------------------------
extern "C" void kernel_launch(void* const* d_in, const int* in_sizes, int n_in,
                              void* d_out, int out_size, void* d_ws, size_t ws_size,
                              hipStream_t stream)
{
  const float* x1 = (const float*)d_in[0];
  const float* x2 = (const float*)d_in[1];
  const float* WQ = (const float*)d_in[2];
  const float* bQ = (const float*)d_in[3];
  const float* WK = (const float*)d_in[4];
  const float* bK = (const float*)d_in[5];
  const float* WV = (const float*)d_in[6];
  const float* bV = (const float*)d_in[7];

  float* out  = (float*)d_out;
  float* Qf   = out;                    // [4,2048,256]
  float* Qhat = out + 2097152;          // [4,2048,256]
  float* attn = out + 4194304;          // [4,2048,4096]

  char* ws = (char*)d_ws;
  bf16* Qb   = (bf16*)(ws + (0ull  << 20));  // 4 MB
  bf16* tQb  = (bf16*)(ws + (4ull  << 20));  // 4 MB
  bf16* Kb   = (bf16*)(ws + (8ull  << 20));  // 8 MB
  bf16* tKb  = (bf16*)(ws + (16ull << 20));  // 8 MB
  bf16* Vt   = (bf16*)(ws + (24ull << 20));  // 8 MB  [b][dk][m]
  bf16* E    = (bf16*)(ws + (32ull << 20));  // 64 MB [b][n][m] bf16 e
  float* partials = (float*)(ws + (96ull << 20));  // 1 MB

  projQ_kernel    <<<dim3(64, 4),   256, 0, stream>>>(x2, WQ, bQ, Qf, Qb, tQb);
  proj_kernel<1>  <<<dim3(128, 4),  256, 0, stream>>>(x1, WK, bK, Kb, tKb);
  proj_kernel<2>  <<<dim3(2, 256),  256, 0, stream>>>(WV, x1, bV, Vt, nullptr);
  scores_kernel   <<<dim3(32, 16, 4), 256, 0, stream>>>(Qb, tQb, Kb, tKb, E, partials);
  qhat_kernel     <<<256, 256, 0, stream>>>(E, Vt, partials, attn, Qhat);
}

// Round 11
// 167.352 us; speedup vs baseline: 1.1369x; 1.1369x over previous
//
#include <hip/hip_runtime.h>
#include <hip/hip_bf16.h>

typedef __bf16 bf16;
typedef __bf16 bf16x4 __attribute__((ext_vector_type(4)));
typedef __bf16 bf16x8 __attribute__((ext_vector_type(8)));
typedef float  f32x4  __attribute__((ext_vector_type(4)));

#define DEVI static __device__ __forceinline__

constexpr int NB = 4;
constexpr int N1 = 4096;
constexpr int N2 = 2048;
constexpr int D  = 256;   // DIM1 = DIM2 = DK

DEVI f32x4 mfma16(bf16x8 a, bf16x8 b, f32x4 c) {
  return __builtin_amdgcn_mfma_f32_16x16x32_bf16(a, b, c, 0, 0, 0);
}

typedef const __attribute__((address_space(1))) void* gas_t;
typedef __attribute__((address_space(3))) void* las_t;

DEVI void gload_lds16(const void* g, void* l) {
  __builtin_amdgcn_global_load_lds((gas_t)g, (las_t)l, 16, 0, 0);
}

DEVI void fence_sched() { __builtin_amdgcn_sched_barrier(0); }

// ---------------------------------------------------------------------------
// Q projection with hi/lo bf16 split for near-fp32 accuracy on the fp32 Q out.
// ---------------------------------------------------------------------------
__global__ __launch_bounds__(256)
void projQ_kernel(const float* __restrict__ A, const float* __restrict__ Bm,
                  const float* __restrict__ bias,
                  float* __restrict__ outF, bf16* __restrict__ out1,
                  bf16* __restrict__ out2)
{
  __shared__ bf16 Ah[128][64], Al[128][64];
  __shared__ bf16 Bh[64][64],  Bl[64][64];
  const int tid  = threadIdx.x;
  const int lane = tid & 63, wid = tid >> 6;
  const int wr = wid >> 1, wc = wid & 1;
  const int m0 = blockIdx.x * 128, n0 = blockIdx.y * 64;

  f32x4 acc[4][2];
#pragma unroll
  for (int i = 0; i < 4; ++i)
#pragma unroll
    for (int j = 0; j < 2; ++j) acc[i][j] = f32x4{0.f, 0.f, 0.f, 0.f};

  for (int kt = 0; kt < 4; ++kt) {
    const int k0 = kt * 64;
    if (kt) __syncthreads();
#pragma unroll
    for (int i = 0; i < 8; ++i) {
      int idx = i * 256 + tid;
      int r = idx >> 4, c4 = idx & 15;
      const float4 v = *(const float4*)(A + (size_t)(m0 + r) * D + k0 + c4 * 4);
      bf16x4 h, l;
      h[0] = (bf16)v.x; h[1] = (bf16)v.y; h[2] = (bf16)v.z; h[3] = (bf16)v.w;
      l[0] = (bf16)(v.x - (float)h[0]); l[1] = (bf16)(v.y - (float)h[1]);
      l[2] = (bf16)(v.z - (float)h[2]); l[3] = (bf16)(v.w - (float)h[3]);
      *(bf16x4*)&Ah[r][c4 * 4] = h;
      *(bf16x4*)&Al[r][c4 * 4] = l;
    }
#pragma unroll
    for (int i = 0; i < 4; ++i) {
      int idx = i * 256 + tid;
      int r = idx >> 4, c4 = idx & 15;
      const float4 v = *(const float4*)(Bm + (size_t)(n0 + r) * D + k0 + c4 * 4);
      bf16x4 h, l;
      h[0] = (bf16)v.x; h[1] = (bf16)v.y; h[2] = (bf16)v.z; h[3] = (bf16)v.w;
      l[0] = (bf16)(v.x - (float)h[0]); l[1] = (bf16)(v.y - (float)h[1]);
      l[2] = (bf16)(v.z - (float)h[2]); l[3] = (bf16)(v.w - (float)h[3]);
      *(bf16x4*)&Bh[r][c4 * 4] = h;
      *(bf16x4*)&Bl[r][c4 * 4] = l;
    }
    __syncthreads();
#pragma unroll
    for (int kc = 0; kc < 2; ++kc) {
      const int ko = kc * 32 + (lane >> 4) * 8;
      bf16x8 ah[4], al[4];
#pragma unroll
      for (int mf = 0; mf < 4; ++mf) {
        ah[mf] = *(bf16x8*)&Ah[wr * 64 + mf * 16 + (lane & 15)][ko];
        al[mf] = *(bf16x8*)&Al[wr * 64 + mf * 16 + (lane & 15)][ko];
      }
#pragma unroll
      for (int nf = 0; nf < 2; ++nf) {
        bf16x8 bh = *(bf16x8*)&Bh[wc * 32 + nf * 16 + (lane & 15)][ko];
        bf16x8 bl = *(bf16x8*)&Bl[wc * 32 + nf * 16 + (lane & 15)][ko];
#pragma unroll
        for (int mf = 0; mf < 4; ++mf) {
          acc[mf][nf] = mfma16(ah[mf], bh, acc[mf][nf]);
          acc[mf][nf] = mfma16(ah[mf], bl, acc[mf][nf]);
          acc[mf][nf] = mfma16(al[mf], bh, acc[mf][nf]);
        }
      }
    }
  }

#pragma unroll
  for (int nf = 0; nf < 2; ++nf) {
    const int col = n0 + wc * 32 + nf * 16 + (lane & 15);
    const float bcol = bias[col];
#pragma unroll
    for (int mf = 0; mf < 4; ++mf) {
#pragma unroll
      for (int r = 0; r < 4; ++r) {
        const int row = m0 + wr * 64 + mf * 16 + (lane >> 4) * 4 + r;
        float v = acc[mf][nf][r] + bcol;
        outF[(size_t)row * D + col] = v;
        out1[(size_t)row * D + col] = (bf16)v;
        out2[(size_t)row * D + col] = (bf16)tanhf(v);
      }
    }
  }
}

// ---------------------------------------------------------------------------
// K / V^T projections (plain bf16 MFMA).
// ---------------------------------------------------------------------------
template<int MODE>
__global__ __launch_bounds__(256)
void proj_kernel(const float* __restrict__ A, const float* __restrict__ Bm,
                 const float* __restrict__ bias,
                 bf16* __restrict__ out1, bf16* __restrict__ out2)
{
  __shared__ bf16 As[128][64];
  __shared__ bf16 Bs[64][64];
  const int tid  = threadIdx.x;
  const int lane = tid & 63, wid = tid >> 6;
  const int wr = wid >> 1, wc = wid & 1;
  const int m0 = blockIdx.x * 128, n0 = blockIdx.y * 64;

  f32x4 acc[4][2];
#pragma unroll
  for (int i = 0; i < 4; ++i)
#pragma unroll
    for (int j = 0; j < 2; ++j) acc[i][j] = f32x4{0.f, 0.f, 0.f, 0.f};

  for (int kt = 0; kt < 4; ++kt) {
    const int k0 = kt * 64;
    if (kt) __syncthreads();
#pragma unroll
    for (int i = 0; i < 8; ++i) {
      int idx = i * 256 + tid;
      int r = idx >> 4, c4 = idx & 15;
      const float4 v = *(const float4*)(A + (size_t)(m0 + r) * D + k0 + c4 * 4);
      bf16x4 bv; bv[0] = (bf16)v.x; bv[1] = (bf16)v.y; bv[2] = (bf16)v.z; bv[3] = (bf16)v.w;
      *(bf16x4*)&As[r][c4 * 4] = bv;
    }
#pragma unroll
    for (int i = 0; i < 4; ++i) {
      int idx = i * 256 + tid;
      int r = idx >> 4, c4 = idx & 15;
      const float4 v = *(const float4*)(Bm + (size_t)(n0 + r) * D + k0 + c4 * 4);
      bf16x4 bv; bv[0] = (bf16)v.x; bv[1] = (bf16)v.y; bv[2] = (bf16)v.z; bv[3] = (bf16)v.w;
      *(bf16x4*)&Bs[r][c4 * 4] = bv;
    }
    __syncthreads();
#pragma unroll
    for (int kc = 0; kc < 2; ++kc) {
      const int ko = kc * 32 + (lane >> 4) * 8;
      bf16x8 a[4];
#pragma unroll
      for (int mf = 0; mf < 4; ++mf)
        a[mf] = *(bf16x8*)&As[wr * 64 + mf * 16 + (lane & 15)][ko];
#pragma unroll
      for (int nf = 0; nf < 2; ++nf) {
        bf16x8 bb = *(bf16x8*)&Bs[wc * 32 + nf * 16 + (lane & 15)][ko];
#pragma unroll
        for (int mf = 0; mf < 4; ++mf) acc[mf][nf] = mfma16(a[mf], bb, acc[mf][nf]);
      }
    }
  }

#pragma unroll
  for (int nf = 0; nf < 2; ++nf) {
    const int col = n0 + wc * 32 + nf * 16 + (lane & 15);
    float bcol = 0.f;
    if constexpr (MODE == 1) bcol = bias[col];
#pragma unroll
    for (int mf = 0; mf < 4; ++mf) {
#pragma unroll
      for (int r = 0; r < 4; ++r) {
        const int row = m0 + wr * 64 + mf * 16 + (lane >> 4) * 4 + r;
        float v = acc[mf][nf][r];
        if constexpr (MODE == 1) {
          v += bcol;
          out1[(size_t)row * D + col] = (bf16)v;
          out2[(size_t)row * D + col] = (bf16)tanhf(v);
        } else {
          v += bias[row];  // row = dk
          out1[(size_t)(col >> 12) * (D * N1) + (size_t)row * N1 + (col & 4095)] = (bf16)v;
        }
      }
    }
  }
}

// ---------------------------------------------------------------------------
// Scores (round-10 variant, under A/B): 256 threads, 4 waves (2n x 2m),
// wave tile 64x64. 128x128 block tile, BK=32, dbuf, counted vmcnt(8).
// ---------------------------------------------------------------------------
__global__ __launch_bounds__(256, 2)
void scores_kernel(const bf16* __restrict__ Qb, const bf16* __restrict__ tQb,
                   const bf16* __restrict__ Kb, const bf16* __restrict__ tKb,
                   bf16* __restrict__ E, float* __restrict__ partials)
{
  __shared__ bf16 SM[2][4][128][32];   // buf, {Qs,tQs,Ks,tKs}
  __shared__ float rowpart[128][2];
  const int tid = threadIdx.x, lane = tid & 63, wid = tid >> 6;
  const int wr = wid >> 1;       // n half (0..1)
  const int wc = wid & 1;        // m half (0..1)
  const int lo16 = lane & 15, hi = lane >> 4;
  const int mt = blockIdx.x, nt = blockIdx.y, b = blockIdx.z;
  const int RQ = b * N2 + nt * 128;
  const int RK = b * N1 + mt * 128;

  f32x4 accS[4][4], accP[4][4];
#pragma unroll
  for (int i = 0; i < 4; ++i)
#pragma unroll
    for (int j = 0; j < 4; ++j) {
      accS[i][j] = f32x4{0.f, 0.f, 0.f, 0.f};
      accP[i][j] = f32x4{0.f, 0.f, 0.f, 0.f};
    }

  auto stage = [&](int kt, int buf) {
#pragma unroll
    for (int i = 0; i < 2; ++i) {
      const int c = i * 256 + tid;          // chunk 0..511 per array
      const int row = c >> 2;               // 0..127
      const int soff = kt * 32 + (((c & 3) ^ ((row >> 1) & 3)) << 3);
      char* dst = (char*)&SM[buf][0][0][0] + c * 16;
      gload_lds16(Qb  + (size_t)(RQ + row) * D + soff, dst);
      gload_lds16(tQb + (size_t)(RQ + row) * D + soff, dst + 8192);
      gload_lds16(Kb  + (size_t)(RK + row) * D + soff, dst + 16384);
      gload_lds16(tKb + (size_t)(RK + row) * D + soff, dst + 24576);
    }
  };

  auto cpt = [&](int buf) {
    bf16x8 aS[4], aT[4];
#pragma unroll
    for (int mf = 0; mf < 4; ++mf) {
      const int row = wr * 64 + mf * 16 + lo16;
      const int ko = (hi ^ ((row >> 1) & 3)) << 3;
      aS[mf] = *(bf16x8*)&SM[buf][0][row][ko];
      aT[mf] = *(bf16x8*)&SM[buf][1][row][ko];
    }
#pragma unroll
    for (int nf = 0; nf < 4; ++nf) {
      const int row = wc * 64 + nf * 16 + lo16;
      const int ko = (hi ^ ((row >> 1) & 3)) << 3;
      bf16x8 bS = *(bf16x8*)&SM[buf][2][row][ko];
      bf16x8 bT = *(bf16x8*)&SM[buf][3][row][ko];
#pragma unroll
      for (int mf = 0; mf < 4; ++mf) {
        accS[mf][nf] = mfma16(aS[mf], bS, accS[mf][nf]);
        accP[mf][nf] = mfma16(aT[mf], bT, accP[mf][nf]);
      }
    }
  };

  stage(0, 0);
  fence_sched();
  int cur = 0;
#pragma unroll
  for (int kt = 0; kt < 8; ++kt) {
    if (kt < 7) {
      stage(kt + 1, cur ^ 1);
      fence_sched();
      asm volatile("s_waitcnt vmcnt(8)\n\ts_barrier" ::: "memory");
    } else {
      asm volatile("s_waitcnt vmcnt(0)\n\ts_barrier" ::: "memory");
    }
    __builtin_amdgcn_s_setprio(1);
    cpt(cur);
    __builtin_amdgcn_s_setprio(0);
    asm volatile("s_barrier" ::: "memory");
    cur ^= 1;
  }

  // epilogue
#pragma unroll
  for (int mf = 0; mf < 4; ++mf) {
    f32x4 rs = f32x4{0.f, 0.f, 0.f, 0.f};
#pragma unroll
    for (int nf = 0; nf < 4; ++nf) {
      const int m_g = mt * 128 + wc * 64 + nf * 16 + lo16;
#pragma unroll
      for (int r = 0; r < 4; ++r) {
        const int n_g = b * N2 + nt * 128 + wr * 64 + mf * 16 + hi * 4 + r;
        float s = accS[mf][nf][r] * (accP[mf][nf][r] + 1.0f) * 0.03125f;
        float e = __expf(s);
        E[(size_t)n_g * N1 + m_g] = (bf16)e;
        rs[r] += e;
      }
    }
#pragma unroll
    for (int r = 0; r < 4; ++r) {
      float v = rs[r];
      v += __shfl_xor(v, 1); v += __shfl_xor(v, 2);
      v += __shfl_xor(v, 4); v += __shfl_xor(v, 8);
      if (lo16 == 0)
        rowpart[wr * 64 + mf * 16 + hi * 4 + r][wc] = v;
    }
  }
  __syncthreads();
  if (tid < 128) {
    float p = rowpart[tid][0] + rowpart[tid][1];
    partials[(size_t)(b * N2 + nt * 128 + tid) * 32 + mt] = p;
  }
}

// ---------------------------------------------------------------------------
// Q_hat partial over an m-quarter (round-9 known-good): BM=128 x BN=256,
// K=1024; 512 threads (4 n-quarters x 2 dk-halves); E+V gload_lds dbuf 96KB;
// counted vmcnt; setprio; XCD-chunked 1D grid.
// ---------------------------------------------------------------------------
__global__ __launch_bounds__(512)
void qhat_kernel(const bf16* __restrict__ E, const bf16* __restrict__ Vt,
                 const float* __restrict__ partials,
                 float* __restrict__ attn, bf16* __restrict__ partQ)
{
  __shared__ bf16 Es[2][128][64];
  __shared__ bf16 Vs[2][256][64];
  __shared__ float rowinv[128];
  const int tid = threadIdx.x, lane = tid & 63, wid = tid >> 6;
  const int lo16 = lane & 15, hi = lane >> 4;
  const int wr = wid & 3;        // n-quarter (0..3)
  const int wh = wid >> 2;       // dk-half (0..1)
  const int wgid = blockIdx.x;
  const int xcd  = wgid & 7;
  const int slot = wgid >> 3;              // 0..31
  const int combo = xcd * 2 + (slot >> 4); // 0..15 -> (q,b)
  const int nt = slot & 15;
  const int q  = combo >> 2;
  const int b  = combo & 3;
  const int n0 = nt * 128;
  const int mq = q * 1024;
  const size_t nbase = (size_t)b * N2 + n0;
  const bf16* vb = Vt + (size_t)b * (D * N1) + mq;

  if (tid < 128) {
    const float* pr = partials + (nbase + tid) * 32;
    f32x4 s4 = *(const f32x4*)pr;
#pragma unroll
    for (int j = 1; j < 8; ++j) s4 += *(const f32x4*)(pr + j * 4);
    rowinv[tid] = 1.0f / (s4[0] + s4[1] + s4[2] + s4[3]);
  }

  auto stage = [&](int ms, int buf) {
#pragma unroll
    for (int i = 0; i < 2; ++i) {
      const int c = i * 512 + tid;
      const int row = c >> 3;
      const int lg = (c & 7) ^ (row & 7);
      gload_lds16(E + (nbase + row) * N1 + mq + ms * 64 + lg * 8,
                  (char*)&Es[buf][0][0] + c * 16);
    }
#pragma unroll
    for (int i = 0; i < 4; ++i) {
      const int c = i * 512 + tid;
      const int row = c >> 3;
      const int lg = (c & 7) ^ (row & 7);
      gload_lds16(vb + (size_t)row * N1 + ms * 64 + lg * 8,
                  (char*)&Vs[buf][0][0] + c * 16);
    }
  };

  f32x4 acc[2][8];
#pragma unroll
  for (int i = 0; i < 2; ++i)
#pragma unroll
    for (int j = 0; j < 8; ++j) acc[i][j] = f32x4{0.f, 0.f, 0.f, 0.f};

  auto cpt = [&](int buf) {
#pragma unroll
    for (int kc = 0; kc < 2; ++kc) {
      bf16x8 a[2];
#pragma unroll
      for (int mf = 0; mf < 2; ++mf) {
        const int row = wr * 32 + mf * 16 + lo16;
        const int ph = (kc * 4 + hi) ^ (row & 7);
        a[mf] = *(bf16x8*)((char*)&Es[buf][0][0] + row * 128 + ph * 16);
      }
#pragma unroll
      for (int nf = 0; nf < 8; ++nf) {
        const int row = wh * 128 + nf * 16 + lo16;
        const int ph = (kc * 4 + hi) ^ (row & 7);
        bf16x8 bb = *(bf16x8*)((char*)&Vs[buf][0][0] + row * 128 + ph * 16);
        acc[0][nf] = mfma16(a[0], bb, acc[0][nf]);
        acc[1][nf] = mfma16(a[1], bb, acc[1][nf]);
      }
    }
  };

  auto attnwrite = [&](int ms, int buf) {
#pragma unroll
    for (int i = 0; i < 2; ++i) {
      const int c = i * 512 + tid;
      const int row = c >> 3;
      const int lg = (c & 7) ^ (row & 7);
      bf16x8 ev = *(bf16x8*)((char*)&Es[buf][0][0] + c * 16);
      const float inv = rowinv[row];
      float v[8];
#pragma unroll
      for (int j = 0; j < 8; ++j) v[j] = (float)ev[j] * inv;
      float* dst = attn + (nbase + row) * N1 + mq + ms * 64 + lg * 8;
      float4 w0 = {v[0], v[1], v[2], v[3]};
      float4 w1 = {v[4], v[5], v[6], v[7]};
      *(float4*)(dst)     = w0;
      *(float4*)(dst + 4) = w1;
    }
  };

  stage(0, 0);
  fence_sched();
  __syncthreads();   // drains stage(0) + rowinv ds_write (one-time full drain)

  int buf = 0;
  for (int ms = 0; ms < 16; ++ms) {
    if (ms < 15) { stage(ms + 1, buf ^ 1); fence_sched(); }
    if (ms == 0)
      asm volatile("s_waitcnt vmcnt(6)\n\ts_barrier" ::: "memory");
    else if (ms < 15)
      asm volatile("s_waitcnt vmcnt(10)\n\ts_barrier" ::: "memory");
    else
      asm volatile("s_waitcnt vmcnt(4)\n\ts_barrier" ::: "memory");
    __builtin_amdgcn_s_setprio(1);
    cpt(buf);
    __builtin_amdgcn_s_setprio(0);
    attnwrite(ms, buf);
    asm volatile("s_barrier" ::: "memory");   // LDS reads done before restage
    buf ^= 1;
  }

  // epilogue: partQ bf16 [q][b][n][dk]
#pragma unroll
  for (int mf = 0; mf < 2; ++mf)
#pragma unroll
    for (int nf = 0; nf < 8; ++nf)
#pragma unroll
      for (int r = 0; r < 4; ++r) {
        const int n  = n0 + wr * 32 + mf * 16 + hi * 4 + r;
        const int dk = wh * 128 + nf * 16 + lo16;
        partQ[((size_t)(q * NB + b) * N2 + n) * D + dk] = (bf16)acc[mf][nf][r];
      }
}

// ---------------------------------------------------------------------------
// reduceQ with fused rinv: 8 rows/block, 32 threads/row; shfl-reduce the 32
// partials, then sum 4 partQ quarters and scale.
// ---------------------------------------------------------------------------
__global__ __launch_bounds__(256)
void reduceQ_kernel(const bf16* __restrict__ P, const float* __restrict__ partials,
                    float* __restrict__ Qhat)
{
  const int tid = threadIdx.x;
  const size_t rn = (size_t)blockIdx.x * 8 + (tid >> 5);  // row 0..8191
  const int j = tid & 31;
  float s = partials[rn * 32 + j];
  s += __shfl_xor(s, 1); s += __shfl_xor(s, 2); s += __shfl_xor(s, 4);
  s += __shfl_xor(s, 8); s += __shfl_xor(s, 16);
  const float inv = 1.0f / s;

  const size_t base = rn * 256 + (size_t)j * 8;
  const size_t S = (size_t)NB * N2 * D;
  bf16x8 p0 = *(const bf16x8*)(P + base);
  bf16x8 p1 = *(const bf16x8*)(P + S + base);
  bf16x8 p2 = *(const bf16x8*)(P + 2 * S + base);
  bf16x8 p3 = *(const bf16x8*)(P + 3 * S + base);
  float o[8];
#pragma unroll
  for (int jj = 0; jj < 8; ++jj)
    o[jj] = (((float)p0[jj] + (float)p1[jj]) + ((float)p2[jj] + (float)p3[jj])) * inv;
  float4 w0 = {o[0], o[1], o[2], o[3]};
  float4 w1 = {o[4], o[5], o[6], o[7]};
  *(float4*)(Qhat + base)     = w0;
  *(float4*)(Qhat + base + 4) = w1;
}

// ---------------------------------------------------------------------------
extern "C" void kernel_launch(void* const* d_in, const int* in_sizes, int n_in,
                              void* d_out, int out_size, void* d_ws, size_t ws_size,
                              hipStream_t stream)
{
  const float* x1 = (const float*)d_in[0];
  const float* x2 = (const float*)d_in[1];
  const float* WQ = (const float*)d_in[2];
  const float* bQ = (const float*)d_in[3];
  const float* WK = (const float*)d_in[4];
  const float* bK = (const float*)d_in[5];
  const float* WV = (const float*)d_in[6];
  const float* bV = (const float*)d_in[7];

  float* out  = (float*)d_out;
  float* Qf   = out;                    // [4,2048,256]
  float* Qhat = out + 2097152;          // [4,2048,256]
  float* attn = out + 4194304;          // [4,2048,4096]

  char* ws = (char*)d_ws;
  bf16* Qb   = (bf16*)(ws + (0ull  << 20));  // 4 MB
  bf16* tQb  = (bf16*)(ws + (4ull  << 20));  // 4 MB
  bf16* Kb   = (bf16*)(ws + (8ull  << 20));  // 8 MB
  bf16* tKb  = (bf16*)(ws + (16ull << 20));  // 8 MB
  bf16* Vt   = (bf16*)(ws + (24ull << 20));  // 8 MB  [b][dk][m]
  bf16* E    = (bf16*)(ws + (32ull << 20));  // 64 MB [b][n][m] bf16 e
  float* partials = (float*)(ws + (96ull << 20));  // 1 MB
  bf16*  partQ    = (bf16*)(ws + (100ull << 20));  // 16 MB [q][b][n][dk]

  projQ_kernel    <<<dim3(64, 4),   256, 0, stream>>>(x2, WQ, bQ, Qf, Qb, tQb);
  proj_kernel<1>  <<<dim3(128, 4),  256, 0, stream>>>(x1, WK, bK, Kb, tKb);
  proj_kernel<2>  <<<dim3(2, 256),  256, 0, stream>>>(WV, x1, bV, Vt, nullptr);
  scores_kernel   <<<dim3(32, 16, 4), 256, 0, stream>>>(Qb, tQb, Kb, tKb, E, partials);
  qhat_kernel     <<<256, 512, 0, stream>>>(E, Vt, partials, attn, partQ);
  reduceQ_kernel  <<<1024, 256, 0, stream>>>(partQ, partials, Qhat);
}

// Round 12
// 147.559 us; speedup vs baseline: 1.2894x; 1.1341x over previous
//
#include <hip/hip_runtime.h>
#include <hip/hip_bf16.h>

typedef __bf16 bf16;
typedef __bf16 bf16x4 __attribute__((ext_vector_type(4)));
typedef __bf16 bf16x8 __attribute__((ext_vector_type(8)));
typedef float  f32x4  __attribute__((ext_vector_type(4)));

#define DEVI static __device__ __forceinline__

constexpr int NB = 4;
constexpr int N1 = 4096;
constexpr int N2 = 2048;
constexpr int D  = 256;   // DIM1 = DIM2 = DK

DEVI f32x4 mfma16(bf16x8 a, bf16x8 b, f32x4 c) {
  return __builtin_amdgcn_mfma_f32_16x16x32_bf16(a, b, c, 0, 0, 0);
}

typedef const __attribute__((address_space(1))) void* gas_t;
typedef __attribute__((address_space(3))) void* las_t;

DEVI void gload_lds16(const void* g, void* l) {
  __builtin_amdgcn_global_load_lds((gas_t)g, (las_t)l, 16, 0, 0);
}

DEVI void fence_sched() { __builtin_amdgcn_sched_barrier(0); }

// ---------------------------------------------------------------------------
// Merged projection kernel: one dispatch, three bodies (blockIdx dispatch).
// Blocks [0,512): K-proj; [512,768): Q-proj (hi/lo split); [768,1280): V^T.
// Shared smem union: 48 KB (Q body) >= 24 KB (K/V body) -> 3 blocks/CU.
// ---------------------------------------------------------------------------
DEVI void projQ_body(bf16* smem,
                     const float* __restrict__ A, const float* __restrict__ Bm,
                     const float* __restrict__ bias,
                     float* __restrict__ outF, bf16* __restrict__ out1,
                     bf16* __restrict__ out2, int bx, int by)
{
  bf16* Ah = smem;              // [128][64]
  bf16* Al = smem + 8192;       // [128][64]
  bf16* Bh = smem + 16384;      // [64][64]
  bf16* Bl = smem + 20480;      // [64][64]
  const int tid  = threadIdx.x;
  const int lane = tid & 63, wid = tid >> 6;
  const int wr = wid >> 1, wc = wid & 1;
  const int m0 = bx * 128, n0 = by * 64;

  f32x4 acc[4][2];
#pragma unroll
  for (int i = 0; i < 4; ++i)
#pragma unroll
    for (int j = 0; j < 2; ++j) acc[i][j] = f32x4{0.f, 0.f, 0.f, 0.f};

  for (int kt = 0; kt < 4; ++kt) {
    const int k0 = kt * 64;
    if (kt) __syncthreads();
#pragma unroll
    for (int i = 0; i < 8; ++i) {
      int idx = i * 256 + tid;
      int r = idx >> 4, c4 = idx & 15;
      const float4 v = *(const float4*)(A + (size_t)(m0 + r) * D + k0 + c4 * 4);
      bf16x4 h, l;
      h[0] = (bf16)v.x; h[1] = (bf16)v.y; h[2] = (bf16)v.z; h[3] = (bf16)v.w;
      l[0] = (bf16)(v.x - (float)h[0]); l[1] = (bf16)(v.y - (float)h[1]);
      l[2] = (bf16)(v.z - (float)h[2]); l[3] = (bf16)(v.w - (float)h[3]);
      *(bf16x4*)&Ah[r * 64 + c4 * 4] = h;
      *(bf16x4*)&Al[r * 64 + c4 * 4] = l;
    }
#pragma unroll
    for (int i = 0; i < 4; ++i) {
      int idx = i * 256 + tid;
      int r = idx >> 4, c4 = idx & 15;
      const float4 v = *(const float4*)(Bm + (size_t)(n0 + r) * D + k0 + c4 * 4);
      bf16x4 h, l;
      h[0] = (bf16)v.x; h[1] = (bf16)v.y; h[2] = (bf16)v.z; h[3] = (bf16)v.w;
      l[0] = (bf16)(v.x - (float)h[0]); l[1] = (bf16)(v.y - (float)h[1]);
      l[2] = (bf16)(v.z - (float)h[2]); l[3] = (bf16)(v.w - (float)h[3]);
      *(bf16x4*)&Bh[r * 64 + c4 * 4] = h;
      *(bf16x4*)&Bl[r * 64 + c4 * 4] = l;
    }
    __syncthreads();
#pragma unroll
    for (int kc = 0; kc < 2; ++kc) {
      const int ko = kc * 32 + (lane >> 4) * 8;
      bf16x8 ah[4], al[4];
#pragma unroll
      for (int mf = 0; mf < 4; ++mf) {
        ah[mf] = *(bf16x8*)&Ah[(wr * 64 + mf * 16 + (lane & 15)) * 64 + ko];
        al[mf] = *(bf16x8*)&Al[(wr * 64 + mf * 16 + (lane & 15)) * 64 + ko];
      }
#pragma unroll
      for (int nf = 0; nf < 2; ++nf) {
        bf16x8 bh = *(bf16x8*)&Bh[(wc * 32 + nf * 16 + (lane & 15)) * 64 + ko];
        bf16x8 bl = *(bf16x8*)&Bl[(wc * 32 + nf * 16 + (lane & 15)) * 64 + ko];
#pragma unroll
        for (int mf = 0; mf < 4; ++mf) {
          acc[mf][nf] = mfma16(ah[mf], bh, acc[mf][nf]);
          acc[mf][nf] = mfma16(ah[mf], bl, acc[mf][nf]);
          acc[mf][nf] = mfma16(al[mf], bh, acc[mf][nf]);
        }
      }
    }
  }

#pragma unroll
  for (int nf = 0; nf < 2; ++nf) {
    const int col = n0 + wc * 32 + nf * 16 + (lane & 15);
    const float bcol = bias[col];
#pragma unroll
    for (int mf = 0; mf < 4; ++mf) {
#pragma unroll
      for (int r = 0; r < 4; ++r) {
        const int row = m0 + wr * 64 + mf * 16 + (lane >> 4) * 4 + r;
        float v = acc[mf][nf][r] + bcol;
        outF[(size_t)row * D + col] = v;
        out1[(size_t)row * D + col] = (bf16)v;
        out2[(size_t)row * D + col] = (bf16)tanhf(v);
      }
    }
  }
}

template<int MODE>  // 1 = K-proj, 2 = V^T-proj
DEVI void proj_body(bf16* smem,
                    const float* __restrict__ A, const float* __restrict__ Bm,
                    const float* __restrict__ bias,
                    bf16* __restrict__ out1, bf16* __restrict__ out2,
                    int bx, int by)
{
  bf16* As = smem;              // [128][64]
  bf16* Bs = smem + 8192;       // [64][64]
  const int tid  = threadIdx.x;
  const int lane = tid & 63, wid = tid >> 6;
  const int wr = wid >> 1, wc = wid & 1;
  const int m0 = bx * 128, n0 = by * 64;

  f32x4 acc[4][2];
#pragma unroll
  for (int i = 0; i < 4; ++i)
#pragma unroll
    for (int j = 0; j < 2; ++j) acc[i][j] = f32x4{0.f, 0.f, 0.f, 0.f};

  for (int kt = 0; kt < 4; ++kt) {
    const int k0 = kt * 64;
    if (kt) __syncthreads();
#pragma unroll
    for (int i = 0; i < 8; ++i) {
      int idx = i * 256 + tid;
      int r = idx >> 4, c4 = idx & 15;
      const float4 v = *(const float4*)(A + (size_t)(m0 + r) * D + k0 + c4 * 4);
      bf16x4 bv; bv[0] = (bf16)v.x; bv[1] = (bf16)v.y; bv[2] = (bf16)v.z; bv[3] = (bf16)v.w;
      *(bf16x4*)&As[r * 64 + c4 * 4] = bv;
    }
#pragma unroll
    for (int i = 0; i < 4; ++i) {
      int idx = i * 256 + tid;
      int r = idx >> 4, c4 = idx & 15;
      const float4 v = *(const float4*)(Bm + (size_t)(n0 + r) * D + k0 + c4 * 4);
      bf16x4 bv; bv[0] = (bf16)v.x; bv[1] = (bf16)v.y; bv[2] = (bf16)v.z; bv[3] = (bf16)v.w;
      *(bf16x4*)&Bs[r * 64 + c4 * 4] = bv;
    }
    __syncthreads();
#pragma unroll
    for (int kc = 0; kc < 2; ++kc) {
      const int ko = kc * 32 + (lane >> 4) * 8;
      bf16x8 a[4];
#pragma unroll
      for (int mf = 0; mf < 4; ++mf)
        a[mf] = *(bf16x8*)&As[(wr * 64 + mf * 16 + (lane & 15)) * 64 + ko];
#pragma unroll
      for (int nf = 0; nf < 2; ++nf) {
        bf16x8 bb = *(bf16x8*)&Bs[(wc * 32 + nf * 16 + (lane & 15)) * 64 + ko];
#pragma unroll
        for (int mf = 0; mf < 4; ++mf) acc[mf][nf] = mfma16(a[mf], bb, acc[mf][nf]);
      }
    }
  }

#pragma unroll
  for (int nf = 0; nf < 2; ++nf) {
    const int col = n0 + wc * 32 + nf * 16 + (lane & 15);
    float bcol = 0.f;
    if constexpr (MODE == 1) bcol = bias[col];
#pragma unroll
    for (int mf = 0; mf < 4; ++mf) {
#pragma unroll
      for (int r = 0; r < 4; ++r) {
        const int row = m0 + wr * 64 + mf * 16 + (lane >> 4) * 4 + r;
        float v = acc[mf][nf][r];
        if constexpr (MODE == 1) {
          v += bcol;
          out1[(size_t)row * D + col] = (bf16)v;
          out2[(size_t)row * D + col] = (bf16)tanhf(v);
        } else {
          v += bias[row];  // row = dk
          out1[(size_t)(col >> 12) * (D * N1) + (size_t)row * N1 + (col & 4095)] = (bf16)v;
        }
      }
    }
  }
}

__global__ __launch_bounds__(256)
void proj_all_kernel(const float* __restrict__ x1, const float* __restrict__ x2,
                     const float* __restrict__ WQ, const float* __restrict__ bQ,
                     const float* __restrict__ WK, const float* __restrict__ bK,
                     const float* __restrict__ WV, const float* __restrict__ bV,
                     float* __restrict__ Qf, bf16* __restrict__ Qb,
                     bf16* __restrict__ tQb, bf16* __restrict__ Kb,
                     bf16* __restrict__ tKb, bf16* __restrict__ Vt)
{
  __shared__ bf16 smem[24576];   // 48 KB union
  const int bid = blockIdx.x;
  if (bid < 512) {
    // K-proj: grid (128 m-tiles, 4 dk-tiles)
    proj_body<1>(smem, x1, WK, bK, Kb, tKb, bid & 127, bid >> 7);
  } else if (bid < 768) {
    // Q-proj: grid (64 m-tiles, 4 dk-tiles)
    const int b2 = bid - 512;
    projQ_body(smem, x2, WQ, bQ, Qf, Qb, tQb, b2 & 63, b2 >> 6);
  } else {
    // V^T-proj: grid (2 dk-tiles, 256 m-tiles)
    const int b3 = bid - 768;
    proj_body<2>(smem, WV, x1, bV, Vt, nullptr, b3 & 1, b3 >> 1);
  }
}

// ---------------------------------------------------------------------------
// Scores (round-11 verified): 256 threads, 4 waves (2n x 2m), wave tile
// 64x64. 128x128 block tile, BK=32, dbuf, counted vmcnt(8), setprio.
// ---------------------------------------------------------------------------
__global__ __launch_bounds__(256, 2)
void scores_kernel(const bf16* __restrict__ Qb, const bf16* __restrict__ tQb,
                   const bf16* __restrict__ Kb, const bf16* __restrict__ tKb,
                   bf16* __restrict__ E, float* __restrict__ partials)
{
  __shared__ bf16 SM[2][4][128][32];   // buf, {Qs,tQs,Ks,tKs}
  __shared__ float rowpart[128][2];
  const int tid = threadIdx.x, lane = tid & 63, wid = tid >> 6;
  const int wr = wid >> 1;       // n half (0..1)
  const int wc = wid & 1;        // m half (0..1)
  const int lo16 = lane & 15, hi = lane >> 4;
  const int mt = blockIdx.x, nt = blockIdx.y, b = blockIdx.z;
  const int RQ = b * N2 + nt * 128;
  const int RK = b * N1 + mt * 128;

  f32x4 accS[4][4], accP[4][4];
#pragma unroll
  for (int i = 0; i < 4; ++i)
#pragma unroll
    for (int j = 0; j < 4; ++j) {
      accS[i][j] = f32x4{0.f, 0.f, 0.f, 0.f};
      accP[i][j] = f32x4{0.f, 0.f, 0.f, 0.f};
    }

  auto stage = [&](int kt, int buf) {
#pragma unroll
    for (int i = 0; i < 2; ++i) {
      const int c = i * 256 + tid;          // chunk 0..511 per array
      const int row = c >> 2;               // 0..127
      const int soff = kt * 32 + (((c & 3) ^ ((row >> 1) & 3)) << 3);
      char* dst = (char*)&SM[buf][0][0][0] + c * 16;
      gload_lds16(Qb  + (size_t)(RQ + row) * D + soff, dst);
      gload_lds16(tQb + (size_t)(RQ + row) * D + soff, dst + 8192);
      gload_lds16(Kb  + (size_t)(RK + row) * D + soff, dst + 16384);
      gload_lds16(tKb + (size_t)(RK + row) * D + soff, dst + 24576);
    }
  };

  auto cpt = [&](int buf) {
    bf16x8 aS[4], aT[4];
#pragma unroll
    for (int mf = 0; mf < 4; ++mf) {
      const int row = wr * 64 + mf * 16 + lo16;
      const int ko = (hi ^ ((row >> 1) & 3)) << 3;
      aS[mf] = *(bf16x8*)&SM[buf][0][row][ko];
      aT[mf] = *(bf16x8*)&SM[buf][1][row][ko];
    }
#pragma unroll
    for (int nf = 0; nf < 4; ++nf) {
      const int row = wc * 64 + nf * 16 + lo16;
      const int ko = (hi ^ ((row >> 1) & 3)) << 3;
      bf16x8 bS = *(bf16x8*)&SM[buf][2][row][ko];
      bf16x8 bT = *(bf16x8*)&SM[buf][3][row][ko];
#pragma unroll
      for (int mf = 0; mf < 4; ++mf) {
        accS[mf][nf] = mfma16(aS[mf], bS, accS[mf][nf]);
        accP[mf][nf] = mfma16(aT[mf], bT, accP[mf][nf]);
      }
    }
  };

  stage(0, 0);
  fence_sched();
  int cur = 0;
#pragma unroll
  for (int kt = 0; kt < 8; ++kt) {
    if (kt < 7) {
      stage(kt + 1, cur ^ 1);
      fence_sched();
      asm volatile("s_waitcnt vmcnt(8)\n\ts_barrier" ::: "memory");
    } else {
      asm volatile("s_waitcnt vmcnt(0)\n\ts_barrier" ::: "memory");
    }
    __builtin_amdgcn_s_setprio(1);
    cpt(cur);
    __builtin_amdgcn_s_setprio(0);
    asm volatile("s_barrier" ::: "memory");
    cur ^= 1;
  }

  // epilogue
#pragma unroll
  for (int mf = 0; mf < 4; ++mf) {
    f32x4 rs = f32x4{0.f, 0.f, 0.f, 0.f};
#pragma unroll
    for (int nf = 0; nf < 4; ++nf) {
      const int m_g = mt * 128 + wc * 64 + nf * 16 + lo16;
#pragma unroll
      for (int r = 0; r < 4; ++r) {
        const int n_g = b * N2 + nt * 128 + wr * 64 + mf * 16 + hi * 4 + r;
        float s = accS[mf][nf][r] * (accP[mf][nf][r] + 1.0f) * 0.03125f;
        float e = __expf(s);
        E[(size_t)n_g * N1 + m_g] = (bf16)e;
        rs[r] += e;
      }
    }
#pragma unroll
    for (int r = 0; r < 4; ++r) {
      float v = rs[r];
      v += __shfl_xor(v, 1); v += __shfl_xor(v, 2);
      v += __shfl_xor(v, 4); v += __shfl_xor(v, 8);
      if (lo16 == 0)
        rowpart[wr * 64 + mf * 16 + hi * 4 + r][wc] = v;
    }
  }
  __syncthreads();
  if (tid < 128) {
    float p = rowpart[tid][0] + rowpart[tid][1];
    partials[(size_t)(b * N2 + nt * 128 + tid) * 32 + mt] = p;
  }
}

// ---------------------------------------------------------------------------
// Q_hat partial over an m-quarter (round-9/11 verified): BM=128 x BN=256,
// K=1024; 512 threads (4 n-quarters x 2 dk-halves); E+V gload_lds dbuf 96KB;
// counted vmcnt; setprio; XCD-chunked 1D grid.
// ---------------------------------------------------------------------------
__global__ __launch_bounds__(512)
void qhat_kernel(const bf16* __restrict__ E, const bf16* __restrict__ Vt,
                 const float* __restrict__ partials,
                 float* __restrict__ attn, bf16* __restrict__ partQ)
{
  __shared__ bf16 Es[2][128][64];
  __shared__ bf16 Vs[2][256][64];
  __shared__ float rowinv[128];
  const int tid = threadIdx.x, lane = tid & 63, wid = tid >> 6;
  const int lo16 = lane & 15, hi = lane >> 4;
  const int wr = wid & 3;        // n-quarter (0..3)
  const int wh = wid >> 2;       // dk-half (0..1)
  const int wgid = blockIdx.x;
  const int xcd  = wgid & 7;
  const int slot = wgid >> 3;              // 0..31
  const int combo = xcd * 2 + (slot >> 4); // 0..15 -> (q,b)
  const int nt = slot & 15;
  const int q  = combo >> 2;
  const int b  = combo & 3;
  const int n0 = nt * 128;
  const int mq = q * 1024;
  const size_t nbase = (size_t)b * N2 + n0;
  const bf16* vb = Vt + (size_t)b * (D * N1) + mq;

  if (tid < 128) {
    const float* pr = partials + (nbase + tid) * 32;
    f32x4 s4 = *(const f32x4*)pr;
#pragma unroll
    for (int j = 1; j < 8; ++j) s4 += *(const f32x4*)(pr + j * 4);
    rowinv[tid] = 1.0f / (s4[0] + s4[1] + s4[2] + s4[3]);
  }

  auto stage = [&](int ms, int buf) {
#pragma unroll
    for (int i = 0; i < 2; ++i) {
      const int c = i * 512 + tid;
      const int row = c >> 3;
      const int lg = (c & 7) ^ (row & 7);
      gload_lds16(E + (nbase + row) * N1 + mq + ms * 64 + lg * 8,
                  (char*)&Es[buf][0][0] + c * 16);
    }
#pragma unroll
    for (int i = 0; i < 4; ++i) {
      const int c = i * 512 + tid;
      const int row = c >> 3;
      const int lg = (c & 7) ^ (row & 7);
      gload_lds16(vb + (size_t)row * N1 + ms * 64 + lg * 8,
                  (char*)&Vs[buf][0][0] + c * 16);
    }
  };

  f32x4 acc[2][8];
#pragma unroll
  for (int i = 0; i < 2; ++i)
#pragma unroll
    for (int j = 0; j < 8; ++j) acc[i][j] = f32x4{0.f, 0.f, 0.f, 0.f};

  auto cpt = [&](int buf) {
#pragma unroll
    for (int kc = 0; kc < 2; ++kc) {
      bf16x8 a[2];
#pragma unroll
      for (int mf = 0; mf < 2; ++mf) {
        const int row = wr * 32 + mf * 16 + lo16;
        const int ph = (kc * 4 + hi) ^ (row & 7);
        a[mf] = *(bf16x8*)((char*)&Es[buf][0][0] + row * 128 + ph * 16);
      }
#pragma unroll
      for (int nf = 0; nf < 8; ++nf) {
        const int row = wh * 128 + nf * 16 + lo16;
        const int ph = (kc * 4 + hi) ^ (row & 7);
        bf16x8 bb = *(bf16x8*)((char*)&Vs[buf][0][0] + row * 128 + ph * 16);
        acc[0][nf] = mfma16(a[0], bb, acc[0][nf]);
        acc[1][nf] = mfma16(a[1], bb, acc[1][nf]);
      }
    }
  };

  auto attnwrite = [&](int ms, int buf) {
#pragma unroll
    for (int i = 0; i < 2; ++i) {
      const int c = i * 512 + tid;
      const int row = c >> 3;
      const int lg = (c & 7) ^ (row & 7);
      bf16x8 ev = *(bf16x8*)((char*)&Es[buf][0][0] + c * 16);
      const float inv = rowinv[row];
      float v[8];
#pragma unroll
      for (int j = 0; j < 8; ++j) v[j] = (float)ev[j] * inv;
      float* dst = attn + (nbase + row) * N1 + mq + ms * 64 + lg * 8;
      float4 w0 = {v[0], v[1], v[2], v[3]};
      float4 w1 = {v[4], v[5], v[6], v[7]};
      *(float4*)(dst)     = w0;
      *(float4*)(dst + 4) = w1;
    }
  };

  stage(0, 0);
  fence_sched();
  __syncthreads();   // drains stage(0) + rowinv ds_write (one-time full drain)

  int buf = 0;
  for (int ms = 0; ms < 16; ++ms) {
    if (ms < 15) { stage(ms + 1, buf ^ 1); fence_sched(); }
    if (ms == 0)
      asm volatile("s_waitcnt vmcnt(6)\n\ts_barrier" ::: "memory");
    else if (ms < 15)
      asm volatile("s_waitcnt vmcnt(10)\n\ts_barrier" ::: "memory");
    else
      asm volatile("s_waitcnt vmcnt(4)\n\ts_barrier" ::: "memory");
    __builtin_amdgcn_s_setprio(1);
    cpt(buf);
    __builtin_amdgcn_s_setprio(0);
    attnwrite(ms, buf);
    asm volatile("s_barrier" ::: "memory");   // LDS reads done before restage
    buf ^= 1;
  }

  // epilogue: partQ bf16 [q][b][n][dk]
#pragma unroll
  for (int mf = 0; mf < 2; ++mf)
#pragma unroll
    for (int nf = 0; nf < 8; ++nf)
#pragma unroll
      for (int r = 0; r < 4; ++r) {
        const int n  = n0 + wr * 32 + mf * 16 + hi * 4 + r;
        const int dk = wh * 128 + nf * 16 + lo16;
        partQ[((size_t)(q * NB + b) * N2 + n) * D + dk] = (bf16)acc[mf][nf][r];
      }
}

// ---------------------------------------------------------------------------
// reduceQ with fused rinv: 8 rows/block, 32 threads/row; shfl-reduce the 32
// partials, then sum 4 partQ quarters and scale.
// ---------------------------------------------------------------------------
__global__ __launch_bounds__(256)
void reduceQ_kernel(const bf16* __restrict__ P, const float* __restrict__ partials,
                    float* __restrict__ Qhat)
{
  const int tid = threadIdx.x;
  const size_t rn = (size_t)blockIdx.x * 8 + (tid >> 5);  // row 0..8191
  const int j = tid & 31;
  float s = partials[rn * 32 + j];
  s += __shfl_xor(s, 1); s += __shfl_xor(s, 2); s += __shfl_xor(s, 4);
  s += __shfl_xor(s, 8); s += __shfl_xor(s, 16);
  const float inv = 1.0f / s;

  const size_t base = rn * 256 + (size_t)j * 8;
  const size_t S = (size_t)NB * N2 * D;
  bf16x8 p0 = *(const bf16x8*)(P + base);
  bf16x8 p1 = *(const bf16x8*)(P + S + base);
  bf16x8 p2 = *(const bf16x8*)(P + 2 * S + base);
  bf16x8 p3 = *(const bf16x8*)(P + 3 * S + base);
  float o[8];
#pragma unroll
  for (int jj = 0; jj < 8; ++jj)
    o[jj] = (((float)p0[jj] + (float)p1[jj]) + ((float)p2[jj] + (float)p3[jj])) * inv;
  float4 w0 = {o[0], o[1], o[2], o[3]};
  float4 w1 = {o[4], o[5], o[6], o[7]};
  *(float4*)(Qhat + base)     = w0;
  *(float4*)(Qhat + base + 4) = w1;
}

// ---------------------------------------------------------------------------
extern "C" void kernel_launch(void* const* d_in, const int* in_sizes, int n_in,
                              void* d_out, int out_size, void* d_ws, size_t ws_size,
                              hipStream_t stream)
{
  const float* x1 = (const float*)d_in[0];
  const float* x2 = (const float*)d_in[1];
  const float* WQ = (const float*)d_in[2];
  const float* bQ = (const float*)d_in[3];
  const float* WK = (const float*)d_in[4];
  const float* bK = (const float*)d_in[5];
  const float* WV = (const float*)d_in[6];
  const float* bV = (const float*)d_in[7];

  float* out  = (float*)d_out;
  float* Qf   = out;                    // [4,2048,256]
  float* Qhat = out + 2097152;          // [4,2048,256]
  float* attn = out + 4194304;          // [4,2048,4096]

  char* ws = (char*)d_ws;
  bf16* Qb   = (bf16*)(ws + (0ull  << 20));  // 4 MB
  bf16* tQb  = (bf16*)(ws + (4ull  << 20));  // 4 MB
  bf16* Kb   = (bf16*)(ws + (8ull  << 20));  // 8 MB
  bf16* tKb  = (bf16*)(ws + (16ull << 20));  // 8 MB
  bf16* Vt   = (bf16*)(ws + (24ull << 20));  // 8 MB  [b][dk][m]
  bf16* E    = (bf16*)(ws + (32ull << 20));  // 64 MB [b][n][m] bf16 e
  float* partials = (float*)(ws + (96ull << 20));  // 1 MB
  bf16*  partQ    = (bf16*)(ws + (100ull << 20));  // 16 MB [q][b][n][dk]

  proj_all_kernel <<<1280, 256, 0, stream>>>(x1, x2, WQ, bQ, WK, bK, WV, bV,
                                             Qf, Qb, tQb, Kb, tKb, Vt);
  scores_kernel   <<<dim3(32, 16, 4), 256, 0, stream>>>(Qb, tQb, Kb, tKb, E, partials);
  qhat_kernel     <<<256, 512, 0, stream>>>(E, Vt, partials, attn, partQ);
  reduceQ_kernel  <<<1024, 256, 0, stream>>>(partQ, partials, Qhat);
}